// Round 1
// 101.549 us; speedup vs baseline: 1.0550x; 1.0550x over previous
//
#include <hip/hip_runtime.h>

#define NN 4096
#define DD 512
#define TT 4096

typedef __bf16 bf16x8 __attribute__((ext_vector_type(8)));
typedef float f32x4 __attribute__((ext_vector_type(4)));

constexpr float INV_TEMP = 1.0f / 0.07f;

#define AS1(p) ((__attribute__((address_space(1))) const void*)(p))
#define AS3(p) ((__attribute__((address_space(3))) void*)(p))

// ---------------- normalize (fp32 -> normalized bf16) + triplet, fused ----------------
// Triplet gathers are independent of the row-normalize work; issuing both per wave lets
// the gather latency hide under the streaming pass. t index space == row index space (T==N).
__global__ __launch_bounds__(256) void k_normtrip(const float* __restrict__ emb,
                                                  __bf16* __restrict__ nemb,
                                                  const int* __restrict__ trip,
                                                  float* __restrict__ tl) {
    int wave = threadIdx.x >> 6, lane = threadIdx.x & 63;
    int row = blockIdx.x * 4 + wave;

    // ---- triplet gathers (issue early, reduce late) ----
    int ia = trip[row * 3 + 0], ip = trip[row * 3 + 1], ig = trip[row * 3 + 2];
    const float4* pa = (const float4*)(emb + (size_t)ia * DD);
    const float4* pp = (const float4*)(emb + (size_t)ip * DD);
    const float4* pn = (const float4*)(emb + (size_t)ig * DD);
    float d1 = 0.0f, d2 = 0.0f;
    #pragma unroll
    for (int j = 0; j < 2; ++j) {
        float4 a = pa[lane * 2 + j];
        float4 p = pp[lane * 2 + j];
        float4 n = pn[lane * 2 + j];
        float dx;
        dx = a.x - p.x + 1e-6f; d1 += dx * dx;
        dx = a.y - p.y + 1e-6f; d1 += dx * dx;
        dx = a.z - p.z + 1e-6f; d1 += dx * dx;
        dx = a.w - p.w + 1e-6f; d1 += dx * dx;
        dx = a.x - n.x + 1e-6f; d2 += dx * dx;
        dx = a.y - n.y + 1e-6f; d2 += dx * dx;
        dx = a.z - n.z + 1e-6f; d2 += dx * dx;
        dx = a.w - n.w + 1e-6f; d2 += dx * dx;
    }

    // ---- normalize ----
    const float4* src = (const float4*)(emb + (size_t)row * DD);
    float4 x0 = src[lane * 2 + 0];
    float4 x1 = src[lane * 2 + 1];
    float ss = x0.x * x0.x + x0.y * x0.y + x0.z * x0.z + x0.w * x0.w +
               x1.x * x1.x + x1.y * x1.y + x1.z * x1.z + x1.w * x1.w;
    #pragma unroll
    for (int m = 1; m < 64; m <<= 1) ss += __shfl_xor(ss, m, 64);
    float inv = 1.0f / fmaxf(sqrtf(ss), 1e-8f);
    bf16x8 v;
    v[0] = (__bf16)(x0.x * inv); v[1] = (__bf16)(x0.y * inv);
    v[2] = (__bf16)(x0.z * inv); v[3] = (__bf16)(x0.w * inv);
    v[4] = (__bf16)(x1.x * inv); v[5] = (__bf16)(x1.y * inv);
    v[6] = (__bf16)(x1.z * inv); v[7] = (__bf16)(x1.w * inv);
    *(bf16x8*)(nemb + (size_t)row * DD + lane * 8) = v;

    // ---- triplet reduce + store ----
    #pragma unroll
    for (int m = 1; m < 64; m <<= 1) {
        d1 += __shfl_xor(d1, m, 64);
        d2 += __shfl_xor(d2, m, 64);
    }
    if (lane == 0) tl[row] = fmaxf(sqrtf(d1) - sqrtf(d2) + 0.5f, 0.0f);
}

// ---------------- contrast: 256x256 tile, BK=64, 8-wave, 8-phase pipelined ----------------
// LDS: 8 half-slots (A/B x half x parity), each 128x64 bf16 = 16KB -> 128KiB + labels.
// Per group g (K-tile g, 4 phases = 4 C-quadrants):
//   P1 (qm0,qn0): ld A-frags(h0)+B-frags(h0); stage Ah1(g+1); MFMA; vmcnt(6)
//   P2 (qm0,qn1): ld B-frags(h1)  [A reused];  stage Bh1(g+1); MFMA
//   P3 (qm1,qn0): ld A-frags(h1)+B-frags(h0);  stage Ah0(g+2); MFMA
//   P4 (qm1,qn1): ld B-frags(h1)  [A reused];  stage Bh0(g+2); MFMA; vmcnt(8)
// WAR safety: each staged slot's previous contents were last read >=1 end-of-phase barrier
// before the stage issue (Ah1/Bh1 prev-parity freed at prev P4; Ah0/Bh0 same-parity freed at
// this group's P2/P3). Residency: vmcnt(6) at end-P1 guarantees loads through prev-P2 landed
// (covers this group's P2/P3/P4 reads); vmcnt(8) at end-P4 guarantees through prev-P4
// (covers next group's P1 reads). Tail: 6,4 then 0. Never vmcnt(0) in steady state.
// T2 swizzle: 16B chunk index XOR (row&7), applied identically to global_load_lds SOURCE
// and ds_read address (involution, LDS dest stays linear).

#define VMW(N) asm volatile("s_waitcnt vmcnt(" #N ")" ::: "memory")
#define NOVM ((void)0)

#define STAGE_A(T, H) do { \
    const __bf16* g_ = nemb + (size_t)(row0 + (H) * 128 + srow) * DD + (T) * 64 + scol; \
    __bf16* l_ = aSm + ((((T) & 1) * 2 + (H)) * 8192) + sdst; \
    __builtin_amdgcn_global_load_lds(AS1(g_), AS3(l_), 16, 0, 0); \
    __builtin_amdgcn_global_load_lds(AS1(g_ + (size_t)8 * DD), AS3(l_ + 512), 16, 0, 0); \
} while (0)

#define STAGE_B(T, H) do { \
    const __bf16* g_ = nemb + (size_t)(col0 + (H) * 128 + srow) * DD + (T) * 64 + scol; \
    __bf16* l_ = bSm + ((((T) & 1) * 2 + (H)) * 8192) + sdst; \
    __builtin_amdgcn_global_load_lds(AS1(g_), AS3(l_), 16, 0, 0); \
    __builtin_amdgcn_global_load_lds(AS1(g_ + (size_t)8 * DD), AS3(l_ + 512), 16, 0, 0); \
} while (0)

#define PHASE(LOADA, QM, QN, STAGE_STMT, VM_STMT) do { \
    const __bf16* aB_ = aSm + (par * 2 + (QM)) * 8192; \
    const __bf16* bB_ = bSm + (par * 2 + (QN)) * 8192; \
    if (LOADA) { \
        _Pragma("unroll") \
        for (int fm_ = 0; fm_ < 4; ++fm_) { \
            _Pragma("unroll") \
            for (int kc_ = 0; kc_ < 2; ++kc_) \
                af[fm_][kc_] = *(const bf16x8*)(aB_ + offA[fm_][kc_]); \
        } \
    } \
    _Pragma("unroll") \
    for (int fn_ = 0; fn_ < 2; ++fn_) { \
        _Pragma("unroll") \
        for (int kc_ = 0; kc_ < 2; ++kc_) \
            bfr[fn_][kc_] = *(const bf16x8*)(bB_ + offB[fn_][kc_]); \
    } \
    STAGE_STMT; \
    asm volatile("" ::: "memory"); \
    __builtin_amdgcn_s_barrier(); \
    asm volatile("s_waitcnt lgkmcnt(0)" ::: "memory"); \
    __builtin_amdgcn_sched_barrier(0); \
    __builtin_amdgcn_s_setprio(1); \
    _Pragma("unroll") \
    for (int kc_ = 0; kc_ < 2; ++kc_) { \
        _Pragma("unroll") \
        for (int fm_ = 0; fm_ < 4; ++fm_) { \
            _Pragma("unroll") \
            for (int fn_ = 0; fn_ < 2; ++fn_) \
                acc[QM][QN][fm_][fn_] = __builtin_amdgcn_mfma_f32_16x16x32_bf16( \
                    af[fm_][kc_], bfr[fn_][kc_], acc[QM][QN][fm_][fn_], 0, 0, 0); \
        } \
    } \
    __builtin_amdgcn_s_setprio(0); \
    __builtin_amdgcn_sched_barrier(0); \
    VM_STMT; \
    asm volatile("" ::: "memory"); \
    __builtin_amdgcn_s_barrier(); \
} while (0)

#define GROUP(G, S12, S34, VM1, VM4) do { \
    int par = (G) & 1; \
    PHASE(1, 0, 0, { if (S12) STAGE_A((G) + 1, 1); }, VM1); \
    PHASE(0, 0, 1, { if (S12) STAGE_B((G) + 1, 1); }, NOVM); \
    PHASE(1, 1, 0, { if (S34) STAGE_A((G) + 2, 0); }, NOVM); \
    PHASE(0, 1, 1, { if (S34) STAGE_B((G) + 2, 0); }, VM4); \
} while (0)

__global__ __launch_bounds__(512, 2) void k_contrast(const __bf16* __restrict__ nemb,
                                                     const int* __restrict__ labels,
                                                     float* __restrict__ posP,
                                                     float* __restrict__ totP,
                                                     float* __restrict__ cntP) {
    __shared__ __attribute__((aligned(16))) __bf16 aSm[4 * 8192];
    __shared__ __attribute__((aligned(16))) __bf16 bSm[4 * 8192];
    __shared__ int rlab[256];
    __shared__ int clab[256];

    int tid = threadIdx.x;
    int lane = tid & 63, wave = tid >> 6;
    int wr = wave >> 2, wc = wave & 3;
    int l15 = lane & 15, quad = lane >> 4;
    int swz = l15 & 7;

    // XCD-aware 2D swizzle: each XCD (bid&7) owns a 4x8 (rowblk x colblk) region
    // -> per-XCD working set ~3MB (fits 4MB L2). Bijective over the 256-block grid.
    int bid = blockIdx.x;
    int xcd = bid & 7, idx = bid >> 3;
    int rowblk = (xcd >> 1) * 4 + (idx >> 3);
    int colblk = (xcd & 1) * 8 + (idx & 7);
    int row0 = rowblk * 256, col0 = colblk * 256;

    if (tid < 256) rlab[tid] = labels[row0 + tid];
    else           clab[tid - 256] = labels[col0 + tid - 256];

    // staging geometry: wave stages 16 rows (2 x global_load_lds of 64 lanes x 16B).
    // LDS dest is linear (row-major [128][64]); SOURCE chunk is pre-swizzled: chunk ^= row&7.
    int srow = wave * 16 + ((tid >> 3) & 7);                 // row within half-tile (j adds 8)
    int scol = ((tid & 7) ^ ((tid >> 3) & 7)) * 8;           // swizzled 16B-chunk * 8 elems
    int sdst = wave * 1024 + (tid & 63) * 8;                 // linear LDS elems (j adds 512)

    // ds_read offsets (elements within a half-slot), swizzled to match the source permutation
    int offA[4][2], offB[2][2];
    #pragma unroll
    for (int fm = 0; fm < 4; ++fm)
        #pragma unroll
        for (int kc = 0; kc < 2; ++kc)
            offA[fm][kc] = (wr * 64 + fm * 16 + l15) * 64 + (((kc * 4 + quad) ^ swz) * 8);
    #pragma unroll
    for (int fn = 0; fn < 2; ++fn)
        #pragma unroll
        for (int kc = 0; kc < 2; ++kc)
            offB[fn][kc] = (wc * 32 + fn * 16 + l15) * 64 + (((kc * 4 + quad) ^ swz) * 8);

    f32x4 acc[2][2][4][2];
    #pragma unroll
    for (int a = 0; a < 2; ++a)
        #pragma unroll
        for (int b = 0; b < 2; ++b)
            #pragma unroll
            for (int c = 0; c < 4; ++c)
                #pragma unroll
                for (int d = 0; d < 2; ++d) {
                    f32x4 z = {0.0f, 0.0f, 0.0f, 0.0f};
                    acc[a][b][c][d] = z;
                }

    bf16x8 af[4][2], bfr[2][2];

    // prologue: 6 half-tiles; vmcnt(8) -> Ah0(0), Bh0(0) resident
    STAGE_A(0, 0); STAGE_B(0, 0);
    STAGE_A(0, 1); STAGE_B(0, 1);
    STAGE_A(1, 0); STAGE_B(1, 0);
    VMW(8);
    asm volatile("" ::: "memory");
    __builtin_amdgcn_s_barrier();

    for (int g = 0; g < 6; ++g) GROUP(g, 1, 1, VMW(6), VMW(8));
    GROUP(6, 1, 0, VMW(6), VMW(4));
    GROUP(7, 0, 0, VMW(0), NOVM);

    // ---- epilogue: exp, mask, per-row partials (64 slots/row: colblk*4 + wc) ----
    #pragma unroll
    for (int qm = 0; qm < 2; ++qm)
    #pragma unroll
    for (int fm = 0; fm < 4; ++fm) {
        int rloc = qm * 128 + wr * 64 + fm * 16 + quad * 4;
        int gibase = row0 + rloc;
        int rl[4];
        #pragma unroll
        for (int v = 0; v < 4; ++v) rl[v] = rlab[rloc + v];
        float tv[4] = {0, 0, 0, 0}, pv[4] = {0, 0, 0, 0}, cv[4] = {0, 0, 0, 0};
        #pragma unroll
        for (int qn = 0; qn < 2; ++qn)
        #pragma unroll
        for (int fn = 0; fn < 2; ++fn) {
            int cloc = qn * 128 + wc * 32 + fn * 16 + l15;
            int cl = clab[cloc];
            int gj = col0 + cloc;
            f32x4 a = acc[qm][qn][fm][fn];
            #pragma unroll
            for (int v = 0; v < 4; ++v) {
                float e = __expf(a[v] * INV_TEMP);
                tv[v] += e;
                bool match = (rl[v] == cl) && ((gibase + v) != gj);
                pv[v] += match ? e : 0.0f;
                cv[v] += match ? 1.0f : 0.0f;
            }
        }
        #pragma unroll
        for (int m = 1; m < 16; m <<= 1) {
            #pragma unroll
            for (int v = 0; v < 4; ++v) {
                tv[v] += __shfl_xor(tv[v], m, 64);
                pv[v] += __shfl_xor(pv[v], m, 64);
                cv[v] += __shfl_xor(cv[v], m, 64);
            }
        }
        if (l15 == 0) {
            #pragma unroll
            for (int v = 0; v < 4; ++v) {
                int o = (gibase + v) * 64 + colblk * 4 + wc;
                posP[o] = pv[v];
                totP[o] = tv[v];
                cntP[o] = cv[v];
            }
        }
    }
}

// ---------------- per-row loss: wave per row, coalesced ----------------
__global__ __launch_bounds__(256) void k_rowloss(const float* __restrict__ posP,
                                                 const float* __restrict__ totP,
                                                 const float* __restrict__ cntP,
                                                 float* __restrict__ rloss,
                                                 float* __restrict__ rvalid) {
    int wave = threadIdx.x >> 6, lane = threadIdx.x & 63;
    int row = blockIdx.x * 4 + wave;
    float p = posP[row * 64 + lane];
    float t = totP[row * 64 + lane];
    float c = cntP[row * 64 + lane];
    #pragma unroll
    for (int m = 1; m < 64; m <<= 1) {
        p += __shfl_xor(p, m, 64);
        t += __shfl_xor(t, m, 64);
        c += __shfl_xor(c, m, 64);
    }
    if (lane == 0) {
        float loss = -logf(p / (t + 1e-8f) + 1e-8f);
        bool valid = c > 0.0f;
        rloss[row] = valid ? loss : 0.0f;
        rvalid[row] = valid ? 1.0f : 0.0f;
    }
}

// ---------------- final reduction ----------------
__global__ __launch_bounds__(256) void k_final(const float* __restrict__ rloss,
                                               const float* __restrict__ rvalid,
                                               const float* __restrict__ tl,
                                               float* __restrict__ out) {
    int tid = threadIdx.x;
    float sl = 0.0f, sv = 0.0f, st = 0.0f;
    for (int i = tid; i < NN; i += 256) {
        sl += rloss[i];
        sv += rvalid[i];
        st += tl[i];
    }
    #pragma unroll
    for (int m = 1; m < 64; m <<= 1) {
        sl += __shfl_xor(sl, m, 64);
        sv += __shfl_xor(sv, m, 64);
        st += __shfl_xor(st, m, 64);
    }
    __shared__ float red[3][4];
    int lane = tid & 63, wave = tid >> 6;
    if (lane == 0) { red[0][wave] = sl; red[1][wave] = sv; red[2][wave] = st; }
    __syncthreads();
    if (tid == 0) {
        float SL = red[0][0] + red[0][1] + red[0][2] + red[0][3];
        float SV = red[1][0] + red[1][1] + red[1][2] + red[1][3];
        float ST = red[2][0] + red[2][1] + red[2][2] + red[2][3];
        float cont = (SV > 0.0f) ? (SL / SV) : 0.0f;
        float trip = ST * (1.0f / (float)TT);
        out[0] = cont + 0.3f * trip;
        out[1] = cont;
        out[2] = trip;
    }
}

extern "C" void kernel_launch(void* const* d_in, const int* in_sizes, int n_in,
                              void* d_out, int out_size, void* d_ws, size_t ws_size,
                              hipStream_t stream) {
    const float* emb = (const float*)d_in[0];
    const int* labels = (const int*)d_in[1];
    const int* trips = (const int*)d_in[2];
    float* out = (float*)d_out;
    char* ws = (char*)d_ws;

    __bf16* nemb  = (__bf16*)(ws);                 // 4096*512*2 = 4194304 B
    float* posP   = (float*)(ws + 4194304);        // 4096*64*4  = 1048576 B
    float* totP   = (float*)(ws + 5242880);        // 1048576 B
    float* cntP   = (float*)(ws + 6291456);        // 1048576 B
    float* rloss  = (float*)(ws + 7340032);        // 16384 B
    float* rvalid = (float*)(ws + 7356416);        // 16384 B
    float* tl     = (float*)(ws + 7372800);        // 16384 B

    k_normtrip<<<NN / 4, 256, 0, stream>>>(emb, nemb, trips, tl);
    k_contrast<<<256, 512, 0, stream>>>(nemb, labels, posP, totP, cntP);
    k_rowloss<<<NN / 4, 256, 0, stream>>>(posP, totP, cntP, rloss, rvalid);
    k_final<<<1, 256, 0, stream>>>(rloss, rvalid, tl, out);
}

// Round 2
// 100.879 us; speedup vs baseline: 1.0620x; 1.0066x over previous
//
#include <hip/hip_runtime.h>

#define NN 4096
#define DD 512
#define TT 4096

typedef __bf16 bf16x8 __attribute__((ext_vector_type(8)));
typedef float f32x4 __attribute__((ext_vector_type(4)));

constexpr float INV_TEMP = 1.0f / 0.07f;

#define AS1(p) ((__attribute__((address_space(1))) const void*)(p))
#define AS3(p) ((__attribute__((address_space(3))) void*)(p))

// ---------------- normalize (fp32 -> normalized bf16) + triplet, fused ----------------
__global__ __launch_bounds__(256) void k_normtrip(const float* __restrict__ emb,
                                                  __bf16* __restrict__ nemb,
                                                  const int* __restrict__ trip,
                                                  float* __restrict__ tl) {
    int wave = threadIdx.x >> 6, lane = threadIdx.x & 63;
    int row = blockIdx.x * 4 + wave;

    // ---- triplet gathers (issue early, reduce late) ----
    int ia = trip[row * 3 + 0], ip = trip[row * 3 + 1], ig = trip[row * 3 + 2];
    const float4* pa = (const float4*)(emb + (size_t)ia * DD);
    const float4* pp = (const float4*)(emb + (size_t)ip * DD);
    const float4* pn = (const float4*)(emb + (size_t)ig * DD);
    float d1 = 0.0f, d2 = 0.0f;
    #pragma unroll
    for (int j = 0; j < 2; ++j) {
        float4 a = pa[lane * 2 + j];
        float4 p = pp[lane * 2 + j];
        float4 n = pn[lane * 2 + j];
        float dx;
        dx = a.x - p.x + 1e-6f; d1 += dx * dx;
        dx = a.y - p.y + 1e-6f; d1 += dx * dx;
        dx = a.z - p.z + 1e-6f; d1 += dx * dx;
        dx = a.w - p.w + 1e-6f; d1 += dx * dx;
        dx = a.x - n.x + 1e-6f; d2 += dx * dx;
        dx = a.y - n.y + 1e-6f; d2 += dx * dx;
        dx = a.z - n.z + 1e-6f; d2 += dx * dx;
        dx = a.w - n.w + 1e-6f; d2 += dx * dx;
    }

    // ---- normalize ----
    const float4* src = (const float4*)(emb + (size_t)row * DD);
    float4 x0 = src[lane * 2 + 0];
    float4 x1 = src[lane * 2 + 1];
    float ss = x0.x * x0.x + x0.y * x0.y + x0.z * x0.z + x0.w * x0.w +
               x1.x * x1.x + x1.y * x1.y + x1.z * x1.z + x1.w * x1.w;
    #pragma unroll
    for (int m = 1; m < 64; m <<= 1) ss += __shfl_xor(ss, m, 64);
    float inv = 1.0f / fmaxf(sqrtf(ss), 1e-8f);
    bf16x8 v;
    v[0] = (__bf16)(x0.x * inv); v[1] = (__bf16)(x0.y * inv);
    v[2] = (__bf16)(x0.z * inv); v[3] = (__bf16)(x0.w * inv);
    v[4] = (__bf16)(x1.x * inv); v[5] = (__bf16)(x1.y * inv);
    v[6] = (__bf16)(x1.z * inv); v[7] = (__bf16)(x1.w * inv);
    *(bf16x8*)(nemb + (size_t)row * DD + lane * 8) = v;

    // ---- triplet reduce + store ----
    #pragma unroll
    for (int m = 1; m < 64; m <<= 1) {
        d1 += __shfl_xor(d1, m, 64);
        d2 += __shfl_xor(d2, m, 64);
    }
    if (lane == 0) tl[row] = fmaxf(sqrtf(d1) - sqrtf(d2) + 0.5f, 0.0f);
}

// ---------------- contrast: 256x256 tile, BK=64, 8-wave, 8-phase pipelined ----------------
// vs previous round (verified-correct, ~35us): (1) barrier1 (pre-MFMA) REMOVED — all slot
// hazards are covered by {per-wave vmcnt(K) -> end-of-phase s_barrier}: RAW (stage->read):
// staged loads drained by the issuing wave's vmcnt before the barrier every wave crosses;
// WAR (read->overwrite): readers passed the previous end-of-phase barrier before the stage
// issues. MFMA needs only the wave's OWN ds_reads => lgkmcnt(0). Dropping barrier1 lets the
// 2 waves/SIMD drift anti-phase so ds_read sections overlap MFMA sections (m114 mechanism).
// (2) register diet: 4 read-offset ints (kc0/kc1 for A,B; fm/fn are +imm), stage bases
// hoisted, groups fully unrolled with literal G so slot bases fold to immediates.
// vmcnt ledger (unchanged): P1-end vmcnt(6), P4-end vmcnt(8); tail 6,4,0. Never 0 steady.

#define VMW(N) asm volatile("s_waitcnt vmcnt(" #N ")" ::: "memory")
#define NOVM ((void)0)

#define STAGE_A(T, H) do { \
    __builtin_amdgcn_global_load_lds(AS1(gA0 + (size_t)((H) * 128) * DD + (T) * 64), \
                                     AS3(lA0 + (((T) & 1) * 2 + (H)) * 8192), 16, 0, 0); \
    __builtin_amdgcn_global_load_lds(AS1(gA0 + (size_t)((H) * 128 + 8) * DD + (T) * 64), \
                                     AS3(lA0 + (((T) & 1) * 2 + (H)) * 8192 + 512), 16, 0, 0); \
} while (0)

#define STAGE_B(T, H) do { \
    __builtin_amdgcn_global_load_lds(AS1(gB0 + (size_t)((H) * 128) * DD + (T) * 64), \
                                     AS3(lB0 + (((T) & 1) * 2 + (H)) * 8192), 16, 0, 0); \
    __builtin_amdgcn_global_load_lds(AS1(gB0 + (size_t)((H) * 128 + 8) * DD + (T) * 64), \
                                     AS3(lB0 + (((T) & 1) * 2 + (H)) * 8192 + 512), 16, 0, 0); \
} while (0)

#define PHASE(PAR, LOADA, QM, QN, STAGE_STMT, VM_STMT) do { \
    const __bf16* aB_ = aSm + ((PAR) * 2 + (QM)) * 8192; \
    const __bf16* bB_ = bSm + ((PAR) * 2 + (QN)) * 8192; \
    if (LOADA) { \
        _Pragma("unroll") \
        for (int fm_ = 0; fm_ < 4; ++fm_) { \
            af[fm_][0] = *(const bf16x8*)(aB_ + fm_ * 1024 + rdA0); \
            af[fm_][1] = *(const bf16x8*)(aB_ + fm_ * 1024 + rdA1); \
        } \
    } \
    _Pragma("unroll") \
    for (int fn_ = 0; fn_ < 2; ++fn_) { \
        bfr[fn_][0] = *(const bf16x8*)(bB_ + fn_ * 1024 + rdB0); \
        bfr[fn_][1] = *(const bf16x8*)(bB_ + fn_ * 1024 + rdB1); \
    } \
    STAGE_STMT; \
    asm volatile("s_waitcnt lgkmcnt(0)" ::: "memory"); \
    __builtin_amdgcn_sched_barrier(0); \
    __builtin_amdgcn_s_setprio(1); \
    _Pragma("unroll") \
    for (int kc_ = 0; kc_ < 2; ++kc_) { \
        _Pragma("unroll") \
        for (int fm_ = 0; fm_ < 4; ++fm_) { \
            _Pragma("unroll") \
            for (int fn_ = 0; fn_ < 2; ++fn_) \
                acc[QM][QN][fm_][fn_] = __builtin_amdgcn_mfma_f32_16x16x32_bf16( \
                    af[fm_][kc_], bfr[fn_][kc_], acc[QM][QN][fm_][fn_], 0, 0, 0); \
        } \
    } \
    __builtin_amdgcn_s_setprio(0); \
    __builtin_amdgcn_sched_barrier(0); \
    VM_STMT; \
    asm volatile("" ::: "memory"); \
    __builtin_amdgcn_s_barrier(); \
} while (0)

#define GROUP(G, S12, S34, VM1, VM4) do { \
    PHASE((G) & 1, 1, 0, 0, { if (S12) STAGE_A((G) + 1, 1); }, VM1); \
    PHASE((G) & 1, 0, 0, 1, { if (S12) STAGE_B((G) + 1, 1); }, NOVM); \
    PHASE((G) & 1, 1, 1, 0, { if (S34) STAGE_A((G) + 2, 0); }, NOVM); \
    PHASE((G) & 1, 0, 1, 1, { if (S34) STAGE_B((G) + 2, 0); }, VM4); \
} while (0)

__global__ __launch_bounds__(512, 2) void k_contrast(const __bf16* __restrict__ nemb,
                                                     const int* __restrict__ labels,
                                                     float* __restrict__ posP,
                                                     float* __restrict__ totP,
                                                     float* __restrict__ cntP) {
    __shared__ __attribute__((aligned(16))) __bf16 aSm[4 * 8192];
    __shared__ __attribute__((aligned(16))) __bf16 bSm[4 * 8192];
    __shared__ int rlab[256];
    __shared__ int clab[256];

    int tid = threadIdx.x;
    int lane = tid & 63, wave = tid >> 6;
    int wr = wave >> 2, wc = wave & 3;
    int l15 = lane & 15, quad = lane >> 4;
    int swz = l15 & 7;

    // XCD-aware 2D swizzle: each XCD (bid&7) owns a 4x8 (rowblk x colblk) region.
    int bid = blockIdx.x;
    int xcd = bid & 7, idx = bid >> 3;
    int rowblk = (xcd >> 1) * 4 + (idx >> 3);
    int colblk = (xcd & 1) * 8 + (idx & 7);
    int row0 = rowblk * 256, col0 = colblk * 256;

    if (tid < 256) rlab[tid] = labels[row0 + tid];
    else           clab[tid - 256] = labels[col0 + tid - 256];

    // staging geometry (unchanged): wave stages 16 rows; LDS dest linear, SOURCE chunk
    // pre-swizzled chunk ^= row&7 (involution with the swizzled ds_read below).
    int srow = wave * 16 + ((tid >> 3) & 7);
    int scol = ((tid & 7) ^ ((tid >> 3) & 7)) * 8;
    const __bf16* gA0 = nemb + (size_t)(row0 + srow) * DD + scol;
    const __bf16* gB0 = nemb + (size_t)(col0 + srow) * DD + scol;
    __bf16* lA0 = aSm + wave * 1024 + (tid & 63) * 8;
    __bf16* lB0 = bSm + wave * 1024 + (tid & 63) * 8;

    // ds_read offsets (elements), kc0/kc1 variants; fm/fn add compile-time +1024*k
    int rdA0 = (wr * 64 + l15) * 64 + ((quad ^ swz) * 8);
    int rdA1 = (wr * 64 + l15) * 64 + (((4 + quad) ^ swz) * 8);
    int rdB0 = (wc * 32 + l15) * 64 + ((quad ^ swz) * 8);
    int rdB1 = (wc * 32 + l15) * 64 + (((4 + quad) ^ swz) * 8);

    f32x4 acc[2][2][4][2];
    #pragma unroll
    for (int a = 0; a < 2; ++a)
        #pragma unroll
        for (int b = 0; b < 2; ++b)
            #pragma unroll
            for (int c = 0; c < 4; ++c)
                #pragma unroll
                for (int d = 0; d < 2; ++d) {
                    f32x4 z = {0.0f, 0.0f, 0.0f, 0.0f};
                    acc[a][b][c][d] = z;
                }

    bf16x8 af[4][2], bfr[2][2];

    // prologue: 6 half-tiles; vmcnt(8) -> Ah0(0), Bh0(0) resident
    STAGE_A(0, 0); STAGE_B(0, 0);
    STAGE_A(0, 1); STAGE_B(0, 1);
    STAGE_A(1, 0); STAGE_B(1, 0);
    VMW(8);
    asm volatile("" ::: "memory");
    __builtin_amdgcn_s_barrier();

    GROUP(0, 1, 1, VMW(6), VMW(8));
    GROUP(1, 1, 1, VMW(6), VMW(8));
    GROUP(2, 1, 1, VMW(6), VMW(8));
    GROUP(3, 1, 1, VMW(6), VMW(8));
    GROUP(4, 1, 1, VMW(6), VMW(8));
    GROUP(5, 1, 1, VMW(6), VMW(8));
    GROUP(6, 1, 0, VMW(6), VMW(4));
    GROUP(7, 0, 0, VMW(0), NOVM);

    // ---- epilogue: exp, mask, per-row partials (64 slots/row: colblk*4 + wc) ----
    #pragma unroll
    for (int qm = 0; qm < 2; ++qm)
    #pragma unroll
    for (int fm = 0; fm < 4; ++fm) {
        int rloc = qm * 128 + wr * 64 + fm * 16 + quad * 4;
        int gibase = row0 + rloc;
        int rl[4];
        #pragma unroll
        for (int v = 0; v < 4; ++v) rl[v] = rlab[rloc + v];
        float tv[4] = {0, 0, 0, 0}, pv[4] = {0, 0, 0, 0}, cv[4] = {0, 0, 0, 0};
        #pragma unroll
        for (int qn = 0; qn < 2; ++qn)
        #pragma unroll
        for (int fn = 0; fn < 2; ++fn) {
            int cloc = qn * 128 + wc * 32 + fn * 16 + l15;
            int cl = clab[cloc];
            int gj = col0 + cloc;
            f32x4 a = acc[qm][qn][fm][fn];
            #pragma unroll
            for (int v = 0; v < 4; ++v) {
                float e = __expf(a[v] * INV_TEMP);
                tv[v] += e;
                bool match = (rl[v] == cl) && ((gibase + v) != gj);
                pv[v] += match ? e : 0.0f;
                cv[v] += match ? 1.0f : 0.0f;
            }
        }
        #pragma unroll
        for (int m = 1; m < 16; m <<= 1) {
            #pragma unroll
            for (int v = 0; v < 4; ++v) {
                tv[v] += __shfl_xor(tv[v], m, 64);
                pv[v] += __shfl_xor(pv[v], m, 64);
                cv[v] += __shfl_xor(cv[v], m, 64);
            }
        }
        if (l15 == 0) {
            #pragma unroll
            for (int v = 0; v < 4; ++v) {
                int o = (gibase + v) * 64 + colblk * 4 + wc;
                posP[o] = pv[v];
                totP[o] = tv[v];
                cntP[o] = cv[v];
            }
        }
    }
}

// ---------------- per-row loss: wave per row, coalesced ----------------
__global__ __launch_bounds__(256) void k_rowloss(const float* __restrict__ posP,
                                                 const float* __restrict__ totP,
                                                 const float* __restrict__ cntP,
                                                 float* __restrict__ rloss,
                                                 float* __restrict__ rvalid) {
    int wave = threadIdx.x >> 6, lane = threadIdx.x & 63;
    int row = blockIdx.x * 4 + wave;
    float p = posP[row * 64 + lane];
    float t = totP[row * 64 + lane];
    float c = cntP[row * 64 + lane];
    #pragma unroll
    for (int m = 1; m < 64; m <<= 1) {
        p += __shfl_xor(p, m, 64);
        t += __shfl_xor(t, m, 64);
        c += __shfl_xor(c, m, 64);
    }
    if (lane == 0) {
        float loss = -logf(p / (t + 1e-8f) + 1e-8f);
        bool valid = c > 0.0f;
        rloss[row] = valid ? loss : 0.0f;
        rvalid[row] = valid ? 1.0f : 0.0f;
    }
}

// ---------------- final reduction ----------------
__global__ __launch_bounds__(256) void k_final(const float* __restrict__ rloss,
                                               const float* __restrict__ rvalid,
                                               const float* __restrict__ tl,
                                               float* __restrict__ out) {
    int tid = threadIdx.x;
    float sl = 0.0f, sv = 0.0f, st = 0.0f;
    for (int i = tid; i < NN; i += 256) {
        sl += rloss[i];
        sv += rvalid[i];
        st += tl[i];
    }
    #pragma unroll
    for (int m = 1; m < 64; m <<= 1) {
        sl += __shfl_xor(sl, m, 64);
        sv += __shfl_xor(sv, m, 64);
        st += __shfl_xor(st, m, 64);
    }
    __shared__ float red[3][4];
    int lane = tid & 63, wave = tid >> 6;
    if (lane == 0) { red[0][wave] = sl; red[1][wave] = sv; red[2][wave] = st; }
    __syncthreads();
    if (tid == 0) {
        float SL = red[0][0] + red[0][1] + red[0][2] + red[0][3];
        float SV = red[1][0] + red[1][1] + red[1][2] + red[1][3];
        float ST = red[2][0] + red[2][1] + red[2][2] + red[2][3];
        float cont = (SV > 0.0f) ? (SL / SV) : 0.0f;
        float trip = ST * (1.0f / (float)TT);
        out[0] = cont + 0.3f * trip;
        out[1] = cont;
        out[2] = trip;
    }
}

extern "C" void kernel_launch(void* const* d_in, const int* in_sizes, int n_in,
                              void* d_out, int out_size, void* d_ws, size_t ws_size,
                              hipStream_t stream) {
    const float* emb = (const float*)d_in[0];
    const int* labels = (const int*)d_in[1];
    const int* trips = (const int*)d_in[2];
    float* out = (float*)d_out;
    char* ws = (char*)d_ws;

    __bf16* nemb  = (__bf16*)(ws);                 // 4096*512*2 = 4194304 B
    float* posP   = (float*)(ws + 4194304);        // 4096*64*4  = 1048576 B
    float* totP   = (float*)(ws + 5242880);        // 1048576 B
    float* cntP   = (float*)(ws + 6291456);        // 1048576 B
    float* rloss  = (float*)(ws + 7340032);        // 16384 B
    float* rvalid = (float*)(ws + 7356416);        // 16384 B
    float* tl     = (float*)(ws + 7372800);        // 16384 B

    k_normtrip<<<NN / 4, 256, 0, stream>>>(emb, nemb, trips, tl);
    k_contrast<<<256, 512, 0, stream>>>(nemb, labels, posP, totP, cntP);
    k_rowloss<<<NN / 4, 256, 0, stream>>>(posP, totP, cntP, rloss, rvalid);
    k_final<<<1, 256, 0, stream>>>(rloss, rvalid, tl, out);
}